// Round 1
// baseline (235.318 us; speedup 1.0000x reference)
//
#include <hip/hip_runtime.h>
#include <math.h>

#define NPTS    131072
#define PPB     32            // points per block (4 waves x 8 points)
#define THREADS 256
#define NBLK    (NPTS / PPB)  // 4096
#define HOFF    (7 * 16384)   // head-weight offset in wsW (bf16 elems)
#define HSZ     (32 * 128)    // head block: 32 rows (6 used), 128 k

typedef __attribute__((ext_vector_type(8)))  short short8;
typedef __attribute__((ext_vector_type(16))) float f32x16;
typedef __attribute__((ext_vector_type(2)))  short s16x2;

union b8cv { short8 v; unsigned u[4]; };

__device__ __forceinline__ unsigned short f2bf(float f) {
  unsigned u = __float_as_uint(f);
  unsigned r = (u + 0x7fffu + ((u >> 16) & 1u)) >> 16;
  return (unsigned short)r;
}
#if defined(__has_builtin)
#if __has_builtin(__builtin_amdgcn_cvt_pk_bf16_f32)
#define HAVE_PK_BF16 1
#endif
#endif
__device__ __forceinline__ unsigned pk2(float lo, float hi) {
#ifdef HAVE_PK_BF16
  auto v = __builtin_amdgcn_cvt_pk_bf16_f32(lo, hi);
  unsigned u; __builtin_memcpy(&u, &v, 4); return u;
#else
  return (unsigned)f2bf(lo) | ((unsigned)f2bf(hi) << 16);
#endif
}
__device__ __forceinline__ void gld16(const unsigned short* g, unsigned short* l) {
  __builtin_amdgcn_global_load_lds(
      (const __attribute__((address_space(1))) unsigned int*)(g),
      (__attribute__((address_space(3))) unsigned int*)(l), 16, 0, 0);
}
// broadcast the value-lane (lane & ~3) element of each 4-lane group: DPP quad_perm[0,0,0,0]
__device__ __forceinline__ float qbcast0(float v) {
  return __int_as_float(
      __builtin_amdgcn_mov_dpp(__float_as_int(v), 0x000, 0xf, 0xf, true));
}
// packed-bf16 ReLU with quad value-lane masking:
// broadcast value lane's packed pair, per-half sign mask (pk_ashr 15),
// zero negative halves via bfi.  4 VALU / 2 elements (was 7).
__device__ __forceinline__ unsigned relu_pk(unsigned p) {
  unsigned vs = (unsigned)__builtin_amdgcn_mov_dpp((int)p, 0x000, 0xf, 0xf, true);
  s16x2 m2; __builtin_memcpy(&m2, &vs, 4);
  m2 = m2 >> 15;                          // 0xFFFF per negative half
  unsigned m; __builtin_memcpy(&m, &m2, 4);
  unsigned r;
  asm("v_bfi_b32 %0, %1, 0, %2" : "=v"(r) : "v"(m), "v"(p));
  return r;
}
__device__ __forceinline__ void cross3(const float a[3], const float b[3], float o[3]) {
  o[0] = a[1]*b[2] - a[2]*b[1];
  o[1] = a[2]*b[0] - a[0]*b[2];
  o[2] = a[0]*b[1] - a[1]*b[0];
}
__device__ __forceinline__ float dot3(const float a[3], const float b[3]) {
  return a[0]*b[0] + a[1]*b[1] + a[2]*b[2];
}

// ---- weights -> bf16 workspace: 7x[128c][128k] identity + heads 32x128 ----
__global__ void convert_weights(const float* __restrict__ W_in,
                                const float* __restrict__ Ws,
                                const float* __restrict__ Ww,
                                const float* __restrict__ Wv,
                                unsigned short* __restrict__ wsW) {
  int idx = blockIdx.x * 256 + threadIdx.x;
  if (idx >= HOFF + HSZ) return;
  float v;
  if (idx < HOFF) {
    int l = idx >> 14, r = idx & 16383, c = r >> 7, k = r & 127;
    if (l == 0) v = (k < 39) ? W_in[c * 39 + k] : 0.0f;
    else        v = Ws[(l - 1) * 16384 + c * 128 + k];
  } else {
    int r = idx - HOFF, o = r >> 7, k = r & 127;
    v = (o < 3) ? Ww[o * 128 + k] : (o < 6) ? Wv[(o - 3) * 128 + k] : 0.0f;
  }
  wsW[idx] = f2bf(v);
}

// DMA a 64-col half-layer (16 KB) into an LDS slot, XOR-chunk-swizzled:
// slot row R, chunk-pos chs holds global chunk chs^(R&15).
__device__ __forceinline__ void dma_half(const unsigned short* __restrict__ g,
                                         unsigned short* lds, int tid) {
  #pragma unroll
  for (int i = 0; i < 4; ++i) {
    int flat = i * 256 + tid;
    int R = flat >> 4, chs = flat & 15, ch = chs ^ (R & 15);
    gld16(g + R * 128 + ch * 8, lds + flat * 8);
  }
}

// One MLP layer, half-slot pipelined, phase-split accumulators, typed short8
// activation registers (direct MFMA operands).  A-frag LDS addresses are
// precomputed per-lane (aoff[] + sig-adjusted base pointers) and shared
// across all 7 layers.  ReLU layers use the packed-bf16 mask path.
template <int NKS, bool LEAKY, bool HASNEXT>
__device__ __forceinline__ void mlp_layer(short8 (&pregv)[8],
                                          unsigned short* s0, unsigned short* s1,
                                          const unsigned short* s0s,
                                          const unsigned short* s1s,
                                          const int (&aoff)[8],
                                          const float* __restrict__ bg,
                                          const unsigned short* __restrict__ Wthis,
                                          const unsigned short* __restrict__ Wnext,
                                          int h, int tid, int lane) {
  // stage this layer's upper half (cols 64-127) into s1; drained at mid-sync
  dma_half(Wthis + 64 * 128, s1, tid);

  const bool isv = (lane & 3) == 0;   // this lane's act row is a value row
  short8 tmp[4];                      // phase-1 results (units 0-63)

  // ---- phase 1: output units 0-63 (tiles mt=0,1) from s0 ----
  {
    f32x16 acc[2];
    #pragma unroll
    for (int mt = 0; mt < 2; ++mt)
      #pragma unroll
      for (int q = 0; q < 4; ++q) {
        float4 bb = *(const float4*)(bg + 32*mt + 16*(q>>1) + 8*h + 4*(q&1));
        acc[mt][4*q+0] = isv ? bb.x : 0.0f;
        acc[mt][4*q+1] = isv ? bb.y : 0.0f;
        acc[mt][4*q+2] = isv ? bb.z : 0.0f;
        acc[mt][4*q+3] = isv ? bb.w : 0.0f;
      }
    #pragma unroll
    for (int ks = 0; ks < NKS; ++ks) {
      #pragma unroll
      for (int m = 0; m < 2; ++m) {
        short8 af = *(const short8*)(s0s + m * 4096 + aoff[ks]);
        acc[m] = __builtin_amdgcn_mfma_f32_32x32x16_bf16(af, pregv[ks], acc[m], 0, 0, 0);
      }
    }
    #pragma unroll
    for (int mt = 0; mt < 2; ++mt)
      #pragma unroll
      for (int qh = 0; qh < 2; ++qh) {
        b8cv cv;
        #pragma unroll
        for (int qs = 0; qs < 2; ++qs) {
          int q = 2*qh + qs;
          if (LEAKY) {
            float pr[4];
            #pragma unroll
            for (int e2 = 0; e2 < 4; ++e2) {
              float post = acc[mt][4*q + e2];
              float vraw = qbcast0(post);
              pr[e2] = vraw > 0.0f ? post : post * 0.01f;
            }
            cv.u[2*qs]     = pk2(pr[0], pr[1]);
            cv.u[2*qs + 1] = pk2(pr[2], pr[3]);
          } else {
            cv.u[2*qs]     = relu_pk(pk2(acc[mt][4*q+0], acc[mt][4*q+1]));
            cv.u[2*qs + 1] = relu_pk(pk2(acc[mt][4*q+2], acc[mt][4*q+3]));
          }
        }
        tmp[2*mt + qh] = cv.v;
      }
  }

  __syncthreads();                       // s0 reads done; drains s1 DMA too
  if (HASNEXT) dma_half(Wnext, s0, tid); // next layer's cols 0-63

  // ---- phase 2: output units 64-127 (tiles mt=2,3) from s1 ----
  {
    f32x16 acc[2];
    #pragma unroll
    for (int mt = 0; mt < 2; ++mt)
      #pragma unroll
      for (int q = 0; q < 4; ++q) {
        float4 bb = *(const float4*)(bg + 32*(2+mt) + 16*(q>>1) + 8*h + 4*(q&1));
        acc[mt][4*q+0] = isv ? bb.x : 0.0f;
        acc[mt][4*q+1] = isv ? bb.y : 0.0f;
        acc[mt][4*q+2] = isv ? bb.z : 0.0f;
        acc[mt][4*q+3] = isv ? bb.w : 0.0f;
      }
    #pragma unroll
    for (int ks = 0; ks < NKS; ++ks) {
      #pragma unroll
      for (int m = 0; m < 2; ++m) {
        short8 af = *(const short8*)(s1s + m * 4096 + aoff[ks]);
        acc[m] = __builtin_amdgcn_mfma_f32_32x32x16_bf16(af, pregv[ks], acc[m], 0, 0, 0);
      }
    }
    // old pregv fully consumed -> write phase-2 results directly
    #pragma unroll
    for (int mt = 0; mt < 2; ++mt)
      #pragma unroll
      for (int qh = 0; qh < 2; ++qh) {
        b8cv cv;
        #pragma unroll
        for (int qs = 0; qs < 2; ++qs) {
          int q = 2*qh + qs;
          if (LEAKY) {
            float pr[4];
            #pragma unroll
            for (int e2 = 0; e2 < 4; ++e2) {
              float post = acc[mt][4*q + e2];
              float vraw = qbcast0(post);
              pr[e2] = vraw > 0.0f ? post : post * 0.01f;
            }
            cv.u[2*qs]     = pk2(pr[0], pr[1]);
            cv.u[2*qs + 1] = pk2(pr[2], pr[3]);
          } else {
            cv.u[2*qs]     = relu_pk(pk2(acc[mt][4*q+0], acc[mt][4*q+1]));
            cv.u[2*qs + 1] = relu_pk(pk2(acc[mt][4*q+2], acc[mt][4*q+3]));
          }
        }
        pregv[4 + 2*mt + qh] = cv.v;
      }
  }

  #pragma unroll
  for (int i = 0; i < 4; ++i) pregv[i] = tmp[i];
  __syncthreads();                       // s1 reads done; drains s0 DMA
}

__global__ __launch_bounds__(THREADS, 4)
void nerfies_mfma(const float* __restrict__ x,
                  const float* __restrict__ b_in,
                  const float* __restrict__ bs,
                  const float* __restrict__ bw,
                  const float* __restrict__ bv,
                  const unsigned short* __restrict__ wsW,
                  const int* __restrict__ iterp,
                  float* __restrict__ out)
{
  __shared__ __align__(16) unsigned short sWl[2][64 * 128];  // 2x16 KB half-slots
  float* sH = (float*)sWl[1];                                // heads alias slot 1

  const int tid  = threadIdx.x;
  const int lane = tid & 63;
  const int wv   = tid >> 6;
  const int c32  = lane & 31;
  const int h    = lane >> 5;
  const int p0   = blockIdx.x * PPB;
  // sigma: swap bits 2<->3 (A-row permutation making next-layer B = identity)
  const int sig  = (c32 & 0x13) | ((c32 & 4) << 1) | ((c32 & 8) >> 1);

  // prologue: stage layer-0 cols 0-63 into slot 0 (covered by posenc below)
  dma_half(wsW, sWl[0], tid);

  // per-lane A-frag addressing, invariant across ALL layers/phases:
  // element offset = sig*128 (row) + m*4096 + aoff[ks]
  int aoff[8];
  #pragma unroll
  for (int ks = 0; ks < 8; ++ks) aoff[ks] = ((2*ks + h) ^ (sig & 15)) << 3;
  const unsigned short* s0s = sWl[0] + sig * 128;
  const unsigned short* s1s = sWl[1] + sig * 128;

  // this lane's act row: r = c32, point = wv*8 + (c32>>2), tangent d = c32&3
  const int d  = c32 & 3;
  const int gp = p0 + wv * 8 + (c32 >> 2);
  float X[3] = { x[gp * 3 + 0], x[gp * 3 + 1], x[gp * 3 + 2] };

  int iraw = iterp[0];
  float it = (iraw > 0 && iraw < 100000000) ? (float)iraw : ((const float*)iterp)[0];
  const float aM = 6.0f * it / 3000.0f;

  // ---- posenc into packed act regs (B-identity unit ordering) ----
  short8 pregv[8];
  #pragma unroll
  for (int j = 4; j < 8; ++j) pregv[j] = (short8)0;
  #pragma unroll
  for (int j = 0; j < 4; ++j) {
    b8cv cv;
    #pragma unroll
    for (int ii = 0; ii < 4; ++ii) {
      int i = 4*j + ii;
      int mt = i >> 3, rr = i & 7, q = rr >> 1, s = rr & 1;
      int u0 = 32*mt + 16*(q>>1) + 8*h + 4*(q&1) + 2*s;
      float vp[2];
      #pragma unroll
      for (int ci = 0; ci < 2; ++ci) {
        int c = u0 + ci;
        float val = 0.0f;
        if (c < 3) {
          val = (d == 0) ? X[c] : ((c == d - 1) ? 1.0f : 0.0f);
        } else if (c < 39) {
          int kk = c - 3;
          int a  = kk / 12;
          int rm = kk - a * 12;
          int t  = rm / 6;
          int jf = rm - t * 6;
          float e2 = exp2f((float)(jf - 3));
          float mj = e2 * 3.14f;
          float tt = fminf(fmaxf(aM - (float)jf, 0.0f), 1.0f);
          float wj = (1.0f - __builtin_amdgcn_cosf(tt * 0.49974652f)) * 0.5f;
          float rev = X[a] * (e2 * 0.49974652f);
          float fr  = rev - floorf(rev);
          float sv = __builtin_amdgcn_sinf(fr);
          float cvv = __builtin_amdgcn_cosf(fr);
          if (d == 0)          val = (t == 0 ? sv : cvv) * wj;
          else if (a == d - 1) val = (t == 0 ? cvv : -sv) * (mj * wj);
        }
        vp[ci] = val;
      }
      cv.u[ii] = pk2(vp[0], vp[1]);
    }
    pregv[j] = cv.v;
  }
  __syncthreads();   // slot0 (layer-0 lower half) landed

  mlp_layer<3, true , true >(pregv, sWl[0], sWl[1], s0s, s1s, aoff, b_in,       wsW + 0*16384, wsW + 1*16384, h, tid, lane);
  mlp_layer<8, false, true >(pregv, sWl[0], sWl[1], s0s, s1s, aoff, bs + 0*128, wsW + 1*16384, wsW + 2*16384, h, tid, lane);
  mlp_layer<8, false, true >(pregv, sWl[0], sWl[1], s0s, s1s, aoff, bs + 1*128, wsW + 2*16384, wsW + 3*16384, h, tid, lane);
  mlp_layer<8, false, true >(pregv, sWl[0], sWl[1], s0s, s1s, aoff, bs + 2*128, wsW + 3*16384, wsW + 4*16384, h, tid, lane);
  mlp_layer<8, false, true >(pregv, sWl[0], sWl[1], s0s, s1s, aoff, bs + 3*128, wsW + 4*16384, wsW + 5*16384, h, tid, lane);
  mlp_layer<8, false, true >(pregv, sWl[0], sWl[1], s0s, s1s, aoff, bs + 4*128, wsW + 5*16384, wsW + 6*16384, h, tid, lane);
  mlp_layer<8, false, false>(pregv, sWl[0], sWl[1], s0s, s1s, aoff, bs + 5*128, wsW + 6*16384, wsW,           h, tid, lane);

  // ---- heads: A = head weights (identity rows o) from L2, B = pregv ----
  {
    f32x16 hacc;
    #pragma unroll
    for (int e = 0; e < 16; ++e) hacc[e] = 0.0f;
    const unsigned short* hw = wsW + HOFF;
    #pragma unroll
    for (int ks = 0; ks < 8; ++ks) {
      short8 afrag = *(const short8*)(hw + c32 * 128 + ks * 16 + 8 * h);
      hacc = __builtin_amdgcn_mfma_f32_32x32x16_bf16(afrag, pregv[ks], hacc, 0, 0, 0);
    }
    int rg = wv * 32 + c32;
    if (h == 0) {   // regs 0..3 = outs o=0..3
      *(float4*)(sH + rg * 8) = make_float4(hacc[0], hacc[1], hacc[2], hacc[3]);
    } else {        // regs 0..1 = outs o=4,5
      *(float2*)(sH + rg * 8 + 4) = make_float2(hacc[0], hacc[1]);
    }
  }
  __syncthreads();

  // ---- SE(3) epilogue + forward-mode Jacobian: 8 points per wave ----
  if (lane < 8) {
    const int p  = wv * 8 + lane;
    const int gpp = p0 + p;
    float XX[3] = { x[gpp*3+0], x[gpp*3+1], x[gpp*3+2] };
    float w[3], v[3], dw[3][3], dv[3][3];
    const int rb = p * 4;
    #pragma unroll
    for (int i = 0; i < 3; ++i) {
      w[i] = sH[rb * 8 + i]     + bw[i];
      v[i] = sH[rb * 8 + 3 + i] + bv[i];
      #pragma unroll
      for (int dd = 0; dd < 3; ++dd) {
        dw[dd][i] = sH[(rb + 1 + dd) * 8 + i];
        dv[dd][i] = sH[(rb + 1 + dd) * 8 + 3 + i];
      }
    }
    float th  = sqrtf(w[0]*w[0] + w[1]*w[1] + w[2]*w[2]);
    float ith = 1.0f / th;
    float u[3]  = { w[0]*ith, w[1]*ith, w[2]*ith };
    float vh[3] = { v[0]*ith, v[1]*ith, v[2]*ith };
    float s = sinf(th), c = cosf(th);
    float C2 = 1.0f - c;
    float ths = th - s;
    float uxx[3]; cross3(u, XX, uxx);
    float udx = dot3(u, XX);
    float uxv[3]; cross3(u, vh, uxv);
    float udv = dot3(u, vh);
    #pragma unroll
    for (int i = 0; i < 3; ++i) {
      float Rx = XX[i] + s * uxx[i] + C2 * (u[i] * udx - XX[i]);
      float tt = th * vh[i] + C2 * uxv[i] + ths * (u[i] * udv - vh[i]);
      out[gpp*3 + i] = Rx + tt;
    }
    float* Jout = out + (size_t)NPTS * 3 + (size_t)gpp * 9;
    #pragma unroll
    for (int dd = 0; dd < 3; ++dd) {
      float dwv[3] = { dw[dd][0], dw[dd][1], dw[dd][2] };
      float dvv[3] = { dv[dd][0], dv[dd][1], dv[dd][2] };
      float dth = dot3(w, dwv) * ith;
      float du[3], dvhv[3];
      #pragma unroll
      for (int i = 0; i < 3; ++i) {
        du[i]   = (dwv[i] - u[i]  * dth) * ith;
        dvhv[i] = (dvv[i] - vh[i] * dth) * ith;
      }
      float ex[3] = { dd == 0 ? 1.0f : 0.0f, dd == 1 ? 1.0f : 0.0f, dd == 2 ? 1.0f : 0.0f };
      float dsv  = c  * dth;
      float dC2  = s  * dth;
      float dths = C2 * dth;
      float duxx[3]; cross3(du, XX, duxx);
      float uxe[3];  cross3(u, ex, uxe);
      float dudx = dot3(du, XX) + u[dd];
      float duxv[3]; cross3(du, vh, duxv);
      float uxdv[3]; cross3(u, dvhv, uxdv);
      float dudv = dot3(du, vh) + dot3(u, dvhv);
      #pragma unroll
      for (int i = 0; i < 3; ++i) {
        float dRx = ex[i] + dsv * uxx[i] + s * (duxx[i] + uxe[i])
                  + dC2 * (u[i] * udx - XX[i])
                  + C2 * (du[i] * udx + u[i] * dudx - ex[i]);
        float dt  = dth * vh[i] + th * dvhv[i] + dC2 * uxv[i]
                  + C2 * (duxv[i] + uxdv[i])
                  + dths * (u[i] * udv - vh[i])
                  + ths * (du[i] * udv + u[i] * dudv - dvhv[i]);
        Jout[i * 3 + dd] = dRx + dt;
      }
    }
  }
}

extern "C" void kernel_launch(void* const* d_in, const int* in_sizes, int n_in,
                              void* d_out, int out_size, void* d_ws, size_t ws_size,
                              hipStream_t stream) {
  const float* x    = (const float*)d_in[0];
  const float* W_in = (const float*)d_in[1];
  const float* b_in = (const float*)d_in[2];
  const float* Ws   = (const float*)d_in[3];
  const float* bs   = (const float*)d_in[4];
  const float* Ww   = (const float*)d_in[5];
  const float* bw   = (const float*)d_in[6];
  const float* Wv   = (const float*)d_in[7];
  const float* bv   = (const float*)d_in[8];
  const int*   itp  = (const int*)d_in[9];
  unsigned short* wsW = (unsigned short*)d_ws;   // (7*16384 + 4096) bf16

  convert_weights<<<dim3((HOFF + HSZ + 255) / 256), dim3(256), 0, stream>>>(
      W_in, Ws, Ww, Wv, wsW);
  nerfies_mfma<<<dim3(NBLK), dim3(THREADS), 0, stream>>>(
      x, b_in, bs, bw, bv, wsW, itp, (float*)d_out);
}

// Round 3
// 206.198 us; speedup vs baseline: 1.1412x; 1.1412x over previous
//
#include <hip/hip_runtime.h>
#include <math.h>

#define NPTS    131072
#define PPB     32            // points per block (4 waves x 8 points)
#define THREADS 256
#define NBLK    (NPTS / PPB)  // 4096
#define HOFF    (7 * 16384)   // head-weight offset in wsW (bf16 elems)
#define HSZ     (32 * 128)    // head block: 32 rows (6 used), 128 k

typedef __attribute__((ext_vector_type(8)))  short short8;
typedef __attribute__((ext_vector_type(16))) float f32x16;
typedef __attribute__((ext_vector_type(2)))  short s16x2;
typedef __attribute__((ext_vector_type(2)))  __bf16 bf16x2v;

union b8cv { short8 v; unsigned u[4]; };

__device__ __forceinline__ unsigned short f2bf(float f) {
  unsigned u = __float_as_uint(f);
  unsigned r = (u + 0x7fffu + ((u >> 16) & 1u)) >> 16;
  return (unsigned short)r;
}
// Native bf16 pack: gfx950 lowers fptrunc f32->bf16 to v_cvt_pk_bf16_f32
// (m240: compiler-native casts beat inline-asm cvt_pk AND get correct
// VALU->DPP hazard handling, which raw inline asm does not).
__device__ __forceinline__ unsigned pk2(float lo, float hi) {
  bf16x2v t;
  t[0] = (__bf16)lo;
  t[1] = (__bf16)hi;
  unsigned u; __builtin_memcpy(&u, &t, 4); return u;
}
__device__ __forceinline__ void gld16(const unsigned short* g, unsigned short* l) {
  __builtin_amdgcn_global_load_lds(
      (const __attribute__((address_space(1))) unsigned int*)(g),
      (__attribute__((address_space(3))) unsigned int*)(l), 16, 0, 0);
}
// broadcast the value-lane (lane & ~3) element of each 4-lane group: DPP quad_perm[0,0,0,0]
__device__ __forceinline__ float qbcast0(float v) {
  return __int_as_float(
      __builtin_amdgcn_mov_dpp(__float_as_int(v), 0x000, 0xf, 0xf, true));
}
// packed-bf16 ReLU with quad value-lane masking:
// broadcast value lane's packed pair, per-half sign mask (pk_ashr 15),
// zero negative halves via bfi.
__device__ __forceinline__ unsigned relu_pk(unsigned p) {
  unsigned vs = (unsigned)__builtin_amdgcn_mov_dpp((int)p, 0x000, 0xf, 0xf, true);
  s16x2 m2; __builtin_memcpy(&m2, &vs, 4);
  m2 = m2 >> 15;                          // 0xFFFF per negative half
  unsigned m; __builtin_memcpy(&m, &m2, 4);
  unsigned r;
  asm("v_bfi_b32 %0, %1, 0, %2" : "=v"(r) : "v"(m), "v"(p));
  return r;
}
__device__ __forceinline__ void cross3(const float a[3], const float b[3], float o[3]) {
  o[0] = a[1]*b[2] - a[2]*b[1];
  o[1] = a[2]*b[0] - a[0]*b[2];
  o[2] = a[0]*b[1] - a[1]*b[0];
}
__device__ __forceinline__ float dot3(const float a[3], const float b[3]) {
  return a[0]*b[0] + a[1]*b[1] + a[2]*b[2];
}

// ---- weights -> bf16 workspace: 7x[128c][128k] identity + heads 32x128 ----
// Layer-0 rows use only k<39 (MFMA reads k<48); k in [64,128) of units 0..13
// is dead space -> biases stuffed there, laid out as bias-MFMA A-rows:
//   biasA[l][mt*32 + rD] = b_l[32mt + 16(q>>1) + 8h + 4(q&1) + e2]
//   with rD = e2 + 8q + 4h  (the MFMA C-row for acc[mt][4q+e2] at half h).
// Flat j = l*128 + mt*32 + rD  ->  wsW elem (j>>6)*128 + 64 + (j&63).
__global__ void convert_weights(const float* __restrict__ W_in,
                                const float* __restrict__ b_in,
                                const float* __restrict__ Ws,
                                const float* __restrict__ bs,
                                const float* __restrict__ Ww,
                                const float* __restrict__ Wv,
                                unsigned short* __restrict__ wsW) {
  int idx = blockIdx.x * 256 + threadIdx.x;
  if (idx >= HOFF + HSZ) return;
  float v;
  if (idx < HOFF) {
    int l = idx >> 14, r = idx & 16383, c = r >> 7, k = r & 127;
    if (l == 0) {
      if (k < 39) {
        v = W_in[c * 39 + k];
      } else if (k >= 64 && c < 14) {
        int j  = c * 64 + (k - 64);          // 0..895
        int lb = j >> 7, rr = j & 127;
        int mt = rr >> 5, rd = rr & 31;
        int e2 = rd & 3, hh = (rd >> 2) & 1, q = rd >> 3;
        int src = 32*mt + 16*(q>>1) + 8*hh + 4*(q&1) + e2;
        v = (lb == 0) ? b_in[src] : bs[(lb - 1) * 128 + src];
      } else {
        v = 0.0f;
      }
    } else {
      v = Ws[(l - 1) * 16384 + c * 128 + k];
    }
  } else {
    int r = idx - HOFF, o = r >> 7, k = r & 127;
    v = (o < 3) ? Ww[o * 128 + k] : (o < 6) ? Wv[(o - 3) * 128 + k] : 0.0f;
  }
  wsW[idx] = f2bf(v);
}

// DMA a 64-row half-layer (16 KB) into an LDS slot, XOR-chunk-swizzled:
// slot row R, chunk-pos chs holds global chunk chs^(R&15).
__device__ __forceinline__ void dma_half(const unsigned short* __restrict__ g,
                                         unsigned short* lds, int tid) {
  #pragma unroll
  for (int i = 0; i < 4; ++i) {
    int flat = i * 256 + tid;
    int R = flat >> 4, chs = flat & 15, ch = chs ^ (R & 15);
    gld16(g + R * 128 + ch * 8, lds + flat * 8);
  }
}

// bias-MFMA A-frag: elem0 = bf16 bias for A-row c32 (both k-halves load the
// same value; bind carries 0.5 at k=0 and k=8 so the rank-1 product adds b).
__device__ __forceinline__ short8 bias_af(const unsigned short* __restrict__ bb,
                                          int off, int c32) {
  b8cv cv;
  cv.u[0] = (unsigned)bb[off + c32];
  cv.u[1] = 0; cv.u[2] = 0; cv.u[3] = 0;
  return cv.v;
}

// One MLP layer, half-slot pipelined, phase-split accumulators, typed short8
// activation registers (direct MFMA operands).  Bias + acc-init via one
// rank-1 MFMA per tile (C = persistent zero tuple Z) -- no cndmask init, no
// per-layer float4 bias loads.  A-frag LDS addresses precomputed per-lane.
template <int NKS, bool LEAKY, bool HASNEXT>
__device__ __forceinline__ void mlp_layer(short8 (&pregv)[8],
                                          unsigned short* s0, unsigned short* s1,
                                          const unsigned short* s0s,
                                          const unsigned short* s1s,
                                          const int (&aoff)[8],
                                          const unsigned short* __restrict__ bb,
                                          const short8 bind, const f32x16& Z,
                                          const unsigned short* __restrict__ Wthis,
                                          const unsigned short* __restrict__ Wnext,
                                          int h, int tid, int c32) {
  // stage this layer's upper half (rows 64-127) into s1; drained at mid-sync
  dma_half(Wthis + 64 * 128, s1, tid);

  short8 tmp[4];                      // phase-1 results (units 0-63)

  // ---- phase 1: output units 0-63 (tiles mt=0,1) from s0 ----
  {
    f32x16 acc[2];
    acc[0] = __builtin_amdgcn_mfma_f32_32x32x16_bf16(bias_af(bb,  64, c32), bind, Z, 0, 0, 0);
    acc[1] = __builtin_amdgcn_mfma_f32_32x32x16_bf16(bias_af(bb,  96, c32), bind, Z, 0, 0, 0);
    #pragma unroll
    for (int ks = 0; ks < NKS; ++ks) {
      #pragma unroll
      for (int m = 0; m < 2; ++m) {
        short8 af = *(const short8*)(s0s + m * 4096 + aoff[ks]);
        acc[m] = __builtin_amdgcn_mfma_f32_32x32x16_bf16(af, pregv[ks], acc[m], 0, 0, 0);
      }
    }
    #pragma unroll
    for (int mt = 0; mt < 2; ++mt)
      #pragma unroll
      for (int qh = 0; qh < 2; ++qh) {
        b8cv cv;
        #pragma unroll
        for (int qs = 0; qs < 2; ++qs) {
          int q = 2*qh + qs;
          if (LEAKY) {
            float pr[4];
            #pragma unroll
            for (int e2 = 0; e2 < 4; ++e2) {
              float post = acc[mt][4*q + e2];
              float vraw = qbcast0(post);
              pr[e2] = vraw > 0.0f ? post : post * 0.01f;
            }
            cv.u[2*qs]     = pk2(pr[0], pr[1]);
            cv.u[2*qs + 1] = pk2(pr[2], pr[3]);
          } else {
            cv.u[2*qs]     = relu_pk(pk2(acc[mt][4*q+0], acc[mt][4*q+1]));
            cv.u[2*qs + 1] = relu_pk(pk2(acc[mt][4*q+2], acc[mt][4*q+3]));
          }
        }
        tmp[2*mt + qh] = cv.v;
      }
  }

  __syncthreads();                       // s0 reads done; drains s1 DMA too
  if (HASNEXT) dma_half(Wnext, s0, tid); // next layer's rows 0-63

  // ---- phase 2: output units 64-127 (tiles mt=2,3) from s1 ----
  {
    f32x16 acc[2];
    acc[0] = __builtin_amdgcn_mfma_f32_32x32x16_bf16(bias_af(bb, 192, c32), bind, Z, 0, 0, 0);
    acc[1] = __builtin_amdgcn_mfma_f32_32x32x16_bf16(bias_af(bb, 224, c32), bind, Z, 0, 0, 0);
    #pragma unroll
    for (int ks = 0; ks < NKS; ++ks) {
      #pragma unroll
      for (int m = 0; m < 2; ++m) {
        short8 af = *(const short8*)(s1s + m * 4096 + aoff[ks]);
        acc[m] = __builtin_amdgcn_mfma_f32_32x32x16_bf16(af, pregv[ks], acc[m], 0, 0, 0);
      }
    }
    // old pregv fully consumed -> write phase-2 results directly
    #pragma unroll
    for (int mt = 0; mt < 2; ++mt)
      #pragma unroll
      for (int qh = 0; qh < 2; ++qh) {
        b8cv cv;
        #pragma unroll
        for (int qs = 0; qs < 2; ++qs) {
          int q = 2*qh + qs;
          if (LEAKY) {
            float pr[4];
            #pragma unroll
            for (int e2 = 0; e2 < 4; ++e2) {
              float post = acc[mt][4*q + e2];
              float vraw = qbcast0(post);
              pr[e2] = vraw > 0.0f ? post : post * 0.01f;
            }
            cv.u[2*qs]     = pk2(pr[0], pr[1]);
            cv.u[2*qs + 1] = pk2(pr[2], pr[3]);
          } else {
            cv.u[2*qs]     = relu_pk(pk2(acc[mt][4*q+0], acc[mt][4*q+1]));
            cv.u[2*qs + 1] = relu_pk(pk2(acc[mt][4*q+2], acc[mt][4*q+3]));
          }
        }
        pregv[4 + 2*mt + qh] = cv.v;
      }
  }

  #pragma unroll
  for (int i = 0; i < 4; ++i) pregv[i] = tmp[i];
  __syncthreads();                       // s1 reads done; drains s0 DMA
}

__global__ __launch_bounds__(THREADS, 4)
void nerfies_mfma(const float* __restrict__ x,
                  const float* __restrict__ bw,
                  const float* __restrict__ bv,
                  const unsigned short* __restrict__ wsW,
                  const int* __restrict__ iterp,
                  float* __restrict__ out)
{
  __shared__ __align__(16) unsigned short sWl[2][64 * 128];  // 2x16 KB half-slots
  float* sH = (float*)sWl[1];                                // heads alias slot 1

  const int tid  = threadIdx.x;
  const int lane = tid & 63;
  const int wv   = tid >> 6;
  const int c32  = lane & 31;
  const int h    = lane >> 5;
  const int p0   = blockIdx.x * PPB;
  // sigma: swap bits 2<->3 (A-row permutation making next-layer B = identity)
  const int sig  = (c32 & 0x13) | ((c32 & 4) << 1) | ((c32 & 8) >> 1);

  // prologue: stage layer-0 rows 0-63 into slot 0 (covered by posenc below)
  dma_half(wsW, sWl[0], tid);

  // per-lane A-frag addressing, invariant across ALL layers/phases:
  // element offset = sig*128 (row) + m*4096 + aoff[ks]
  int aoff[8];
  #pragma unroll
  for (int ks = 0; ks < 8; ++ks) aoff[ks] = ((2*ks + h) ^ (sig & 15)) << 3;
  const unsigned short* s0s = sWl[0] + sig * 128;
  const unsigned short* s1s = sWl[1] + sig * 128;

  // persistent zero C-operand for first-MFMA-of-chain (zeroed ONCE)
  f32x16 Z;
  #pragma unroll
  for (int e = 0; e < 16; ++e) Z[e] = 0.0f;
  // bias-MFMA B-frag: 0.5 at k in {0,8} (elem0 of both halves), value cols only
  short8 bind;
  {
    b8cv cv;
    cv.u[0] = ((c32 & 3) == 0) ? 0x3F00u : 0u;
    cv.u[1] = 0; cv.u[2] = 0; cv.u[3] = 0;
    bind = cv.v;
  }

  // this lane's act row: r = c32, point = wv*8 + (c32>>2), tangent d = c32&3
  const int d  = c32 & 3;
  const int gp = p0 + wv * 8 + (c32 >> 2);
  float X[3] = { x[gp * 3 + 0], x[gp * 3 + 1], x[gp * 3 + 2] };

  int iraw = iterp[0];
  float it = (iraw > 0 && iraw < 100000000) ? (float)iraw : ((const float*)iterp)[0];
  const float aM = 6.0f * it / 3000.0f;

  // ---- posenc into packed act regs (B-identity unit ordering) ----
  short8 pregv[8];
  #pragma unroll
  for (int j = 4; j < 8; ++j) pregv[j] = (short8)0;
  #pragma unroll
  for (int j = 0; j < 4; ++j) {
    b8cv cv;
    #pragma unroll
    for (int ii = 0; ii < 4; ++ii) {
      int i = 4*j + ii;
      int mt = i >> 3, rr = i & 7, q = rr >> 1, s = rr & 1;
      int u0 = 32*mt + 16*(q>>1) + 8*h + 4*(q&1) + 2*s;
      float vp[2];
      #pragma unroll
      for (int ci = 0; ci < 2; ++ci) {
        int c = u0 + ci;
        float val = 0.0f;
        if (c < 3) {
          val = (d == 0) ? X[c] : ((c == d - 1) ? 1.0f : 0.0f);
        } else if (c < 39) {
          int kk = c - 3;
          int a  = kk / 12;
          int rm = kk - a * 12;
          int t  = rm / 6;
          int jf = rm - t * 6;
          float e2 = exp2f((float)(jf - 3));
          float mj = e2 * 3.14f;
          float tt = fminf(fmaxf(aM - (float)jf, 0.0f), 1.0f);
          float wj = (1.0f - __builtin_amdgcn_cosf(tt * 0.49974652f)) * 0.5f;
          float rev = X[a] * (e2 * 0.49974652f);
          float fr  = rev - floorf(rev);
          float sv = __builtin_amdgcn_sinf(fr);
          float cvv = __builtin_amdgcn_cosf(fr);
          if (d == 0)          val = (t == 0 ? sv : cvv) * wj;
          else if (a == d - 1) val = (t == 0 ? cvv : -sv) * (mj * wj);
        }
        vp[ci] = val;
      }
      cv.u[ii] = pk2(vp[0], vp[1]);
    }
    pregv[j] = cv.v;
  }
  __syncthreads();   // slot0 (layer-0 lower half) landed

  mlp_layer<3, true , true >(pregv, sWl[0], sWl[1], s0s, s1s, aoff, wsW + 0*256, bind, Z, wsW + 0*16384, wsW + 1*16384, h, tid, c32);
  mlp_layer<8, false, true >(pregv, sWl[0], sWl[1], s0s, s1s, aoff, wsW + 1*256, bind, Z, wsW + 1*16384, wsW + 2*16384, h, tid, c32);
  mlp_layer<8, false, true >(pregv, sWl[0], sWl[1], s0s, s1s, aoff, wsW + 2*256, bind, Z, wsW + 2*16384, wsW + 3*16384, h, tid, c32);
  mlp_layer<8, false, true >(pregv, sWl[0], sWl[1], s0s, s1s, aoff, wsW + 3*256, bind, Z, wsW + 3*16384, wsW + 4*16384, h, tid, c32);
  mlp_layer<8, false, true >(pregv, sWl[0], sWl[1], s0s, s1s, aoff, wsW + 4*256, bind, Z, wsW + 4*16384, wsW + 5*16384, h, tid, c32);
  mlp_layer<8, false, true >(pregv, sWl[0], sWl[1], s0s, s1s, aoff, wsW + 5*256, bind, Z, wsW + 5*16384, wsW + 6*16384, h, tid, c32);
  mlp_layer<8, false, false>(pregv, sWl[0], sWl[1], s0s, s1s, aoff, wsW + 6*256, bind, Z, wsW + 6*16384, wsW,           h, tid, c32);

  // ---- heads: A = head weights (identity rows o) from L2, B = pregv ----
  {
    const unsigned short* hw = wsW + HOFF;
    short8 af0 = *(const short8*)(hw + c32 * 128 + 8 * h);
    f32x16 hacc = __builtin_amdgcn_mfma_f32_32x32x16_bf16(af0, pregv[0], Z, 0, 0, 0);
    #pragma unroll
    for (int ks = 1; ks < 8; ++ks) {
      short8 afrag = *(const short8*)(hw + c32 * 128 + ks * 16 + 8 * h);
      hacc = __builtin_amdgcn_mfma_f32_32x32x16_bf16(afrag, pregv[ks], hacc, 0, 0, 0);
    }
    int rg = wv * 32 + c32;
    if (h == 0) {   // regs 0..3 = outs o=0..3
      *(float4*)(sH + rg * 8) = make_float4(hacc[0], hacc[1], hacc[2], hacc[3]);
    } else {        // regs 0..1 = outs o=4,5
      *(float2*)(sH + rg * 8 + 4) = make_float2(hacc[0], hacc[1]);
    }
  }
  __syncthreads();

  // ---- SE(3) epilogue + forward-mode Jacobian: 8 points per wave ----
  if (lane < 8) {
    const int p  = wv * 8 + lane;
    const int gpp = p0 + p;
    float XX[3] = { x[gpp*3+0], x[gpp*3+1], x[gpp*3+2] };
    float w[3], v[3], dw[3][3], dv[3][3];
    const int rb = p * 4;
    #pragma unroll
    for (int i = 0; i < 3; ++i) {
      w[i] = sH[rb * 8 + i]     + bw[i];
      v[i] = sH[rb * 8 + 3 + i] + bv[i];
      #pragma unroll
      for (int dd = 0; dd < 3; ++dd) {
        dw[dd][i] = sH[(rb + 1 + dd) * 8 + i];
        dv[dd][i] = sH[(rb + 1 + dd) * 8 + 3 + i];
      }
    }
    float th  = sqrtf(w[0]*w[0] + w[1]*w[1] + w[2]*w[2]);
    float ith = 1.0f / th;
    float u[3]  = { w[0]*ith, w[1]*ith, w[2]*ith };
    float vh[3] = { v[0]*ith, v[1]*ith, v[2]*ith };
    float s = sinf(th), c = cosf(th);
    float C2 = 1.0f - c;
    float ths = th - s;
    float uxx[3]; cross3(u, XX, uxx);
    float udx = dot3(u, XX);
    float uxv[3]; cross3(u, vh, uxv);
    float udv = dot3(u, vh);
    #pragma unroll
    for (int i = 0; i < 3; ++i) {
      float Rx = XX[i] + s * uxx[i] + C2 * (u[i] * udx - XX[i]);
      float tt = th * vh[i] + C2 * uxv[i] + ths * (u[i] * udv - vh[i]);
      out[gpp*3 + i] = Rx + tt;
    }
    float* Jout = out + (size_t)NPTS * 3 + (size_t)gpp * 9;
    #pragma unroll
    for (int dd = 0; dd < 3; ++dd) {
      float dwv[3] = { dw[dd][0], dw[dd][1], dw[dd][2] };
      float dvv[3] = { dv[dd][0], dv[dd][1], dv[dd][2] };
      float dth = dot3(w, dwv) * ith;
      float du[3], dvhv[3];
      #pragma unroll
      for (int i = 0; i < 3; ++i) {
        du[i]   = (dwv[i] - u[i]  * dth) * ith;
        dvhv[i] = (dvv[i] - vh[i] * dth) * ith;
      }
      float ex[3] = { dd == 0 ? 1.0f : 0.0f, dd == 1 ? 1.0f : 0.0f, dd == 2 ? 1.0f : 0.0f };
      float dsv  = c  * dth;
      float dC2  = s  * dth;
      float dths = C2 * dth;
      float duxx[3]; cross3(du, XX, duxx);
      float uxe[3];  cross3(u, ex, uxe);
      float dudx = dot3(du, XX) + u[dd];
      float duxv[3]; cross3(du, vh, duxv);
      float uxdv[3]; cross3(u, dvhv, uxdv);
      float dudv = dot3(du, vh) + dot3(u, dvhv);
      #pragma unroll
      for (int i = 0; i < 3; ++i) {
        float dRx = ex[i] + dsv * uxx[i] + s * (duxx[i] + uxe[i])
                  + dC2 * (u[i] * udx - XX[i])
                  + C2 * (du[i] * udx + u[i] * dudx - ex[i]);
        float dt  = dth * vh[i] + th * dvhv[i] + dC2 * uxv[i]
                  + C2 * (duxv[i] + uxdv[i])
                  + dths * (u[i] * udv - vh[i])
                  + ths * (du[i] * udv + u[i] * dudv - dvhv[i]);
        Jout[i * 3 + dd] = dRx + dt;
      }
    }
  }
}

extern "C" void kernel_launch(void* const* d_in, const int* in_sizes, int n_in,
                              void* d_out, int out_size, void* d_ws, size_t ws_size,
                              hipStream_t stream) {
  const float* x    = (const float*)d_in[0];
  const float* W_in = (const float*)d_in[1];
  const float* b_in = (const float*)d_in[2];
  const float* Ws   = (const float*)d_in[3];
  const float* bs   = (const float*)d_in[4];
  const float* Ww   = (const float*)d_in[5];
  const float* bw   = (const float*)d_in[6];
  const float* Wv   = (const float*)d_in[7];
  const float* bv   = (const float*)d_in[8];
  const int*   itp  = (const int*)d_in[9];
  unsigned short* wsW = (unsigned short*)d_ws;   // (7*16384 + 4096) bf16

  convert_weights<<<dim3((HOFF + HSZ + 255) / 256), dim3(256), 0, stream>>>(
      W_in, b_in, Ws, bs, Ww, Wv, wsW);
  nerfies_mfma<<<dim3(NBLK), dim3(THREADS), 0, stream>>>(
      x, bw, bv, wsW, itp, (float*)d_out);
}

// Round 4
// 186.553 us; speedup vs baseline: 1.2614x; 1.1053x over previous
//
#include <hip/hip_runtime.h>
#include <math.h>

#define NPTS    131072
#define PPB     64            // points per block (4 waves x 16 points, 2 B-tiles/wave)
#define THREADS 256
#define NBLK    (NPTS / PPB)  // 2048
#define HOFF    (7 * 16384)   // head-weight offset in wsW (bf16 elems)
#define HSZ     (32 * 128)    // head block: 32 rows (6 used), 128 k

typedef __attribute__((ext_vector_type(8)))  short short8;
typedef __attribute__((ext_vector_type(16))) float f32x16;
typedef __attribute__((ext_vector_type(2)))  short s16x2;
typedef __attribute__((ext_vector_type(2)))  __bf16 bf16x2v;

union b8cv { short8 v; unsigned u[4]; };

__device__ __forceinline__ unsigned short f2bf(float f) {
  unsigned u = __float_as_uint(f);
  unsigned r = (u + 0x7fffu + ((u >> 16) & 1u)) >> 16;
  return (unsigned short)r;
}
// Native bf16 pack: gfx950 lowers fptrunc f32->bf16 to v_cvt_pk_bf16_f32
// (compiler-native casts get correct VALU->DPP hazard handling).
__device__ __forceinline__ unsigned pk2(float lo, float hi) {
  bf16x2v t;
  t[0] = (__bf16)lo;
  t[1] = (__bf16)hi;
  unsigned u; __builtin_memcpy(&u, &t, 4); return u;
}
__device__ __forceinline__ void gld16(const unsigned short* g, unsigned short* l) {
  __builtin_amdgcn_global_load_lds(
      (const __attribute__((address_space(1))) unsigned int*)(g),
      (__attribute__((address_space(3))) unsigned int*)(l), 16, 0, 0);
}
// broadcast the value-lane (lane & ~3) element of each 4-lane group: DPP quad_perm[0,0,0,0]
__device__ __forceinline__ float qbcast0(float v) {
  return __int_as_float(
      __builtin_amdgcn_mov_dpp(__float_as_int(v), 0x000, 0xf, 0xf, true));
}
// packed-bf16 ReLU with quad value-lane masking
__device__ __forceinline__ unsigned relu_pk(unsigned p) {
  unsigned vs = (unsigned)__builtin_amdgcn_mov_dpp((int)p, 0x000, 0xf, 0xf, true);
  s16x2 m2; __builtin_memcpy(&m2, &vs, 4);
  m2 = m2 >> 15;                          // 0xFFFF per negative half
  unsigned m; __builtin_memcpy(&m, &m2, 4);
  unsigned r;
  asm("v_bfi_b32 %0, %1, 0, %2" : "=v"(r) : "v"(m), "v"(p));
  return r;
}
__device__ __forceinline__ void cross3(const float a[3], const float b[3], float o[3]) {
  o[0] = a[1]*b[2] - a[2]*b[1];
  o[1] = a[2]*b[0] - a[0]*b[2];
  o[2] = a[0]*b[1] - a[1]*b[0];
}
__device__ __forceinline__ float dot3(const float a[3], const float b[3]) {
  return a[0]*b[0] + a[1]*b[1] + a[2]*b[2];
}

// ---- weights -> bf16 workspace: 7x[128c][128k] identity + heads 32x128 ----
// Biases stuffed into layer-0's dead k>=64 space (see r3 derivation):
//   flat j = l*128 + mt*32 + rD -> wsW elem (j>>6)*128 + 64 + (j&63).
__global__ void convert_weights(const float* __restrict__ W_in,
                                const float* __restrict__ b_in,
                                const float* __restrict__ Ws,
                                const float* __restrict__ bs,
                                const float* __restrict__ Ww,
                                const float* __restrict__ Wv,
                                unsigned short* __restrict__ wsW) {
  int idx = blockIdx.x * 256 + threadIdx.x;
  if (idx >= HOFF + HSZ) return;
  float v;
  if (idx < HOFF) {
    int l = idx >> 14, r = idx & 16383, c = r >> 7, k = r & 127;
    if (l == 0) {
      if (k < 39) {
        v = W_in[c * 39 + k];
      } else if (k >= 64 && c < 14) {
        int j  = c * 64 + (k - 64);          // 0..895
        int lb = j >> 7, rr = j & 127;
        int mt = rr >> 5, rd = rr & 31;
        int e2 = rd & 3, hh = (rd >> 2) & 1, q = rd >> 3;
        int src = 32*mt + 16*(q>>1) + 8*hh + 4*(q&1) + e2;
        v = (lb == 0) ? b_in[src] : bs[(lb - 1) * 128 + src];
      } else {
        v = 0.0f;
      }
    } else {
      v = Ws[(l - 1) * 16384 + c * 128 + k];
    }
  } else {
    int r = idx - HOFF, o = r >> 7, k = r & 127;
    v = (o < 3) ? Ww[o * 128 + k] : (o < 6) ? Wv[(o - 3) * 128 + k] : 0.0f;
  }
  wsW[idx] = f2bf(v);
}

// DMA a 64-row half-layer (16 KB) into an LDS slot, XOR-chunk-swizzled:
// slot row R, chunk-pos chs holds global chunk chs^(R&15).
__device__ __forceinline__ void dma_half(const unsigned short* __restrict__ g,
                                         unsigned short* lds, int tid) {
  #pragma unroll
  for (int i = 0; i < 4; ++i) {
    int flat = i * 256 + tid;
    int R = flat >> 4, chs = flat & 15, ch = chs ^ (R & 15);
    gld16(g + R * 128 + ch * 8, lds + flat * 8);
  }
}

// bias-MFMA A-frag: elem0 = bf16 bias for A-row c32
__device__ __forceinline__ short8 bias_af(const unsigned short* __restrict__ bb,
                                          int off, int c32) {
  b8cv cv;
  cv.u[0] = (unsigned)bb[off + c32];
  cv.u[1] = 0; cv.u[2] = 0; cv.u[3] = 0;
  return cv.v;
}

// activation + pack one tile's phase results: acc[2] (64 units) -> dst[0..3]
template <bool LEAKY>
__device__ __forceinline__ void act_pack(const f32x16 (&acc)[2], short8* dst) {
  #pragma unroll
  for (int mt = 0; mt < 2; ++mt)
    #pragma unroll
    for (int qh = 0; qh < 2; ++qh) {
      b8cv cv;
      #pragma unroll
      for (int qs = 0; qs < 2; ++qs) {
        int q = 2*qh + qs;
        if (LEAKY) {
          float pr[4];
          #pragma unroll
          for (int e2 = 0; e2 < 4; ++e2) {
            float post = acc[mt][4*q + e2];
            float vraw = qbcast0(post);
            pr[e2] = vraw > 0.0f ? post : post * 0.01f;
          }
          cv.u[2*qs]     = pk2(pr[0], pr[1]);
          cv.u[2*qs + 1] = pk2(pr[2], pr[3]);
        } else {
          cv.u[2*qs]     = relu_pk(pk2(acc[mt][4*q+0], acc[mt][4*q+1]));
          cv.u[2*qs + 1] = relu_pk(pk2(acc[mt][4*q+2], acc[mt][4*q+3]));
        }
      }
      dst[2*mt + qh] = cv.v;
    }
}

// One MLP layer for TWO B-tiles (16 points/wave): each A-frag ds_read feeds
// two MFMAs -> LDS read traffic per point is halved vs the 1-tile version.
// Bias + acc-init via rank-1 MFMA (C = persistent zero tuple Z); bias frag
// loaded once per m-tile and shared by both B-tiles.
template <int NKS, bool LEAKY, bool HASNEXT>
__device__ __forceinline__ void mlp_layer(short8 (&pgA)[8], short8 (&pgB)[8],
                                          const unsigned short* s0s,
                                          const unsigned short* s1s,
                                          unsigned short* s0w, unsigned short* s1w,
                                          const int (&aoff)[8],
                                          const unsigned short* __restrict__ bb,
                                          const short8 bind, const f32x16& Z,
                                          const unsigned short* __restrict__ Wthis,
                                          const unsigned short* __restrict__ Wnext,
                                          int tid, int c32) {
  // stage this layer's upper half (units 64-127) into s1; drained at mid-sync
  dma_half(Wthis + 64 * 128, s1w, tid);

  short8 tA[4], tB[4];                // phase-1 results (units 0-63)

  // ---- phase 1: output units 0-63 (tiles mt=0,1) from s0 ----
  {
    f32x16 aA[2], aB[2];
    short8 bf0 = bias_af(bb,  64, c32);
    short8 bf1 = bias_af(bb,  96, c32);
    aA[0] = __builtin_amdgcn_mfma_f32_32x32x16_bf16(bf0, bind, Z, 0, 0, 0);
    aB[0] = __builtin_amdgcn_mfma_f32_32x32x16_bf16(bf0, bind, Z, 0, 0, 0);
    aA[1] = __builtin_amdgcn_mfma_f32_32x32x16_bf16(bf1, bind, Z, 0, 0, 0);
    aB[1] = __builtin_amdgcn_mfma_f32_32x32x16_bf16(bf1, bind, Z, 0, 0, 0);
    #pragma unroll
    for (int ks = 0; ks < NKS; ++ks) {
      #pragma unroll
      for (int m = 0; m < 2; ++m) {
        short8 af = *(const short8*)(s0s + m * 4096 + aoff[ks]);
        aA[m] = __builtin_amdgcn_mfma_f32_32x32x16_bf16(af, pgA[ks], aA[m], 0, 0, 0);
        aB[m] = __builtin_amdgcn_mfma_f32_32x32x16_bf16(af, pgB[ks], aB[m], 0, 0, 0);
      }
    }
    act_pack<LEAKY>(aA, tA);
    act_pack<LEAKY>(aB, tB);
  }

  __syncthreads();                        // s0 reads done; drains s1 DMA too
  if (HASNEXT) dma_half(Wnext, s0w, tid); // next layer's units 0-63

  // ---- phase 2: output units 64-127 (tiles mt=2,3) from s1 ----
  {
    f32x16 aA[2], aB[2];
    short8 bf2 = bias_af(bb, 192, c32);
    short8 bf3 = bias_af(bb, 224, c32);
    aA[0] = __builtin_amdgcn_mfma_f32_32x32x16_bf16(bf2, bind, Z, 0, 0, 0);
    aB[0] = __builtin_amdgcn_mfma_f32_32x32x16_bf16(bf2, bind, Z, 0, 0, 0);
    aA[1] = __builtin_amdgcn_mfma_f32_32x32x16_bf16(bf3, bind, Z, 0, 0, 0);
    aB[1] = __builtin_amdgcn_mfma_f32_32x32x16_bf16(bf3, bind, Z, 0, 0, 0);
    #pragma unroll
    for (int ks = 0; ks < NKS; ++ks) {
      #pragma unroll
      for (int m = 0; m < 2; ++m) {
        short8 af = *(const short8*)(s1s + m * 4096 + aoff[ks]);
        aA[m] = __builtin_amdgcn_mfma_f32_32x32x16_bf16(af, pgA[ks], aA[m], 0, 0, 0);
        aB[m] = __builtin_amdgcn_mfma_f32_32x32x16_bf16(af, pgB[ks], aB[m], 0, 0, 0);
      }
    }
    // old pg fully consumed -> write phase-2 results directly
    act_pack<LEAKY>(aA, &pgA[4]);
    act_pack<LEAKY>(aB, &pgB[4]);
  }

  #pragma unroll
  for (int i = 0; i < 4; ++i) { pgA[i] = tA[i]; pgB[i] = tB[i]; }
  __syncthreads();                       // s1 reads done; drains s0 DMA
}

// posenc for one point-group into packed act regs (B-identity unit ordering)
__device__ __forceinline__ void posenc_pack(const float X[3], int d, int h,
                                            float aM, short8* pg) {
  #pragma unroll
  for (int j = 4; j < 8; ++j) pg[j] = (short8)0;
  #pragma unroll
  for (int j = 0; j < 4; ++j) {
    b8cv cv;
    #pragma unroll
    for (int ii = 0; ii < 4; ++ii) {
      int i = 4*j + ii;
      int mt = i >> 3, rr = i & 7, q = rr >> 1, s = rr & 1;
      int u0 = 32*mt + 16*(q>>1) + 8*h + 4*(q&1) + 2*s;
      float vp[2];
      #pragma unroll
      for (int ci = 0; ci < 2; ++ci) {
        int c = u0 + ci;
        float val = 0.0f;
        if (c < 3) {
          val = (d == 0) ? X[c] : ((c == d - 1) ? 1.0f : 0.0f);
        } else if (c < 39) {
          int kk = c - 3;
          int a  = kk / 12;
          int rm = kk - a * 12;
          int t  = rm / 6;
          int jf = rm - t * 6;
          float e2 = exp2f((float)(jf - 3));
          float mj = e2 * 3.14f;
          float tt = fminf(fmaxf(aM - (float)jf, 0.0f), 1.0f);
          float wj = (1.0f - __builtin_amdgcn_cosf(tt * 0.49974652f)) * 0.5f;
          float rev = X[a] * (e2 * 0.49974652f);
          float fr  = rev - floorf(rev);
          float sv = __builtin_amdgcn_sinf(fr);
          float cvv = __builtin_amdgcn_cosf(fr);
          if (d == 0)          val = (t == 0 ? sv : cvv) * wj;
          else if (a == d - 1) val = (t == 0 ? cvv : -sv) * (mj * wj);
        }
        vp[ci] = val;
      }
      cv.u[ii] = pk2(vp[0], vp[1]);
    }
    pg[j] = cv.v;
  }
}

__global__ __launch_bounds__(THREADS, 2)
void nerfies_mfma(const float* __restrict__ x,
                  const float* __restrict__ bw,
                  const float* __restrict__ bv,
                  const unsigned short* __restrict__ wsW,
                  const int* __restrict__ iterp,
                  float* __restrict__ out)
{
  __shared__ __align__(16) unsigned short sWl[2][64 * 128];  // 2x16 KB half-slots
  float* sH = (float*)sWl[1];                                // heads alias slot 1

  const int tid  = threadIdx.x;
  const int lane = tid & 63;
  const int wv   = tid >> 6;
  const int c32  = lane & 31;
  const int h    = lane >> 5;
  const int p0   = blockIdx.x * PPB;
  // sigma: swap bits 2<->3 (A-row permutation making next-layer B = identity)
  const int sig  = (c32 & 0x13) | ((c32 & 4) << 1) | ((c32 & 8) >> 1);

  // prologue: stage layer-0 units 0-63 into slot 0 (covered by posenc below)
  dma_half(wsW, sWl[0], tid);

  // per-lane A-frag addressing, invariant across ALL layers/phases
  int aoff[8];
  #pragma unroll
  for (int ks = 0; ks < 8; ++ks) aoff[ks] = ((2*ks + h) ^ (sig & 15)) << 3;
  const unsigned short* s0s = sWl[0] + sig * 128;
  const unsigned short* s1s = sWl[1] + sig * 128;

  // persistent zero C-operand (zeroed ONCE)
  f32x16 Z;
  #pragma unroll
  for (int e = 0; e < 16; ++e) Z[e] = 0.0f;
  // bias-MFMA B-frag: 0.5 at k in {0,8} (elem0 of both halves), value cols only
  short8 bind;
  {
    b8cv cv;
    cv.u[0] = ((c32 & 3) == 0) ? 0x3F00u : 0u;
    cv.u[1] = 0; cv.u[2] = 0; cv.u[3] = 0;
    bind = cv.v;
  }

  // lane's act row: point-group A = wv*16 + (c32>>2), group B = +8, tangent d
  const int d   = c32 & 3;
  const int gpA = p0 + wv * 16 + (c32 >> 2);
  const int gpB = gpA + 8;
  float XA[3] = { x[gpA * 3 + 0], x[gpA * 3 + 1], x[gpA * 3 + 2] };
  float XB[3] = { x[gpB * 3 + 0], x[gpB * 3 + 1], x[gpB * 3 + 2] };

  int iraw = iterp[0];
  float it = (iraw > 0 && iraw < 100000000) ? (float)iraw : ((const float*)iterp)[0];
  const float aM = 6.0f * it / 3000.0f;

  short8 pgA[8], pgB[8];
  posenc_pack(XA, d, h, aM, pgA);
  posenc_pack(XB, d, h, aM, pgB);
  __syncthreads();   // slot0 (layer-0 lower half) landed

  mlp_layer<3, true , true >(pgA, pgB, s0s, s1s, sWl[0], sWl[1], aoff, wsW + 0*256, bind, Z, wsW + 0*16384, wsW + 1*16384, tid, c32);
  mlp_layer<8, false, true >(pgA, pgB, s0s, s1s, sWl[0], sWl[1], aoff, wsW + 1*256, bind, Z, wsW + 1*16384, wsW + 2*16384, tid, c32);
  mlp_layer<8, false, true >(pgA, pgB, s0s, s1s, sWl[0], sWl[1], aoff, wsW + 2*256, bind, Z, wsW + 2*16384, wsW + 3*16384, tid, c32);
  mlp_layer<8, false, true >(pgA, pgB, s0s, s1s, sWl[0], sWl[1], aoff, wsW + 3*256, bind, Z, wsW + 3*16384, wsW + 4*16384, tid, c32);
  mlp_layer<8, false, true >(pgA, pgB, s0s, s1s, sWl[0], sWl[1], aoff, wsW + 4*256, bind, Z, wsW + 4*16384, wsW + 5*16384, tid, c32);
  mlp_layer<8, false, true >(pgA, pgB, s0s, s1s, sWl[0], sWl[1], aoff, wsW + 5*256, bind, Z, wsW + 5*16384, wsW + 6*16384, tid, c32);
  mlp_layer<8, false, false>(pgA, pgB, s0s, s1s, sWl[0], sWl[1], aoff, wsW + 6*256, bind, Z, wsW + 6*16384, wsW,           tid, c32);

  // ---- heads: A = head weights from L2 (shared by both B-tiles) ----
  {
    const unsigned short* hw = wsW + HOFF;
    short8 af0 = *(const short8*)(hw + c32 * 128 + 8 * h);
    f32x16 hA = __builtin_amdgcn_mfma_f32_32x32x16_bf16(af0, pgA[0], Z, 0, 0, 0);
    f32x16 hB = __builtin_amdgcn_mfma_f32_32x32x16_bf16(af0, pgB[0], Z, 0, 0, 0);
    #pragma unroll
    for (int ks = 1; ks < 8; ++ks) {
      short8 afrag = *(const short8*)(hw + c32 * 128 + ks * 16 + 8 * h);
      hA = __builtin_amdgcn_mfma_f32_32x32x16_bf16(afrag, pgA[ks], hA, 0, 0, 0);
      hB = __builtin_amdgcn_mfma_f32_32x32x16_bf16(afrag, pgB[ks], hB, 0, 0, 0);
    }
    int rgA = wv * 64 + c32;        // group A rows
    int rgB = rgA + 32;             // group B rows
    if (h == 0) {   // regs 0..3 = outs o=0..3
      *(float4*)(sH + rgA * 8) = make_float4(hA[0], hA[1], hA[2], hA[3]);
      *(float4*)(sH + rgB * 8) = make_float4(hB[0], hB[1], hB[2], hB[3]);
    } else {        // regs 0..1 = outs o=4,5
      *(float2*)(sH + rgA * 8 + 4) = make_float2(hA[0], hA[1]);
      *(float2*)(sH + rgB * 8 + 4) = make_float2(hB[0], hB[1]);
    }
  }
  __syncthreads();

  // ---- SE(3) epilogue + forward-mode Jacobian: 16 points per wave ----
  if (lane < 16) {
    const int p   = lane;
    const int g   = p >> 3, pi = p & 7;
    const int gpp = p0 + wv * 16 + p;
    const int rb  = wv * 64 + g * 32 + pi * 4;   // value row; +1+dd = tangent rows
    float XX[3] = { x[gpp*3+0], x[gpp*3+1], x[gpp*3+2] };
    float w[3], v[3], dw[3][3], dv[3][3];
    #pragma unroll
    for (int i = 0; i < 3; ++i) {
      w[i] = sH[rb * 8 + i]     + bw[i];
      v[i] = sH[rb * 8 + 3 + i] + bv[i];
      #pragma unroll
      for (int dd = 0; dd < 3; ++dd) {
        dw[dd][i] = sH[(rb + 1 + dd) * 8 + i];
        dv[dd][i] = sH[(rb + 1 + dd) * 8 + 3 + i];
      }
    }
    float th  = sqrtf(w[0]*w[0] + w[1]*w[1] + w[2]*w[2]);
    float ith = 1.0f / th;
    float u[3]  = { w[0]*ith, w[1]*ith, w[2]*ith };
    float vh[3] = { v[0]*ith, v[1]*ith, v[2]*ith };
    float s = sinf(th), c = cosf(th);
    float C2 = 1.0f - c;
    float ths = th - s;
    float uxx[3]; cross3(u, XX, uxx);
    float udx = dot3(u, XX);
    float uxv[3]; cross3(u, vh, uxv);
    float udv = dot3(u, vh);
    #pragma unroll
    for (int i = 0; i < 3; ++i) {
      float Rx = XX[i] + s * uxx[i] + C2 * (u[i] * udx - XX[i]);
      float tt = th * vh[i] + C2 * uxv[i] + ths * (u[i] * udv - vh[i]);
      out[gpp*3 + i] = Rx + tt;
    }
    float* Jout = out + (size_t)NPTS * 3 + (size_t)gpp * 9;
    #pragma unroll
    for (int dd = 0; dd < 3; ++dd) {
      float dwv[3] = { dw[dd][0], dw[dd][1], dw[dd][2] };
      float dvv[3] = { dv[dd][0], dv[dd][1], dv[dd][2] };
      float dth = dot3(w, dwv) * ith;
      float du[3], dvhv[3];
      #pragma unroll
      for (int i = 0; i < 3; ++i) {
        du[i]   = (dwv[i] - u[i]  * dth) * ith;
        dvhv[i] = (dvv[i] - vh[i] * dth) * ith;
      }
      float ex[3] = { dd == 0 ? 1.0f : 0.0f, dd == 1 ? 1.0f : 0.0f, dd == 2 ? 1.0f : 0.0f };
      float dsv  = c  * dth;
      float dC2  = s  * dth;
      float dths = C2 * dth;
      float duxx[3]; cross3(du, XX, duxx);
      float uxe[3];  cross3(u, ex, uxe);
      float dudx = dot3(du, XX) + u[dd];
      float duxv[3]; cross3(du, vh, duxv);
      float uxdv[3]; cross3(u, dvhv, uxdv);
      float dudv = dot3(du, vh) + dot3(u, dvhv);
      #pragma unroll
      for (int i = 0; i < 3; ++i) {
        float dRx = ex[i] + dsv * uxx[i] + s * (duxx[i] + uxe[i])
                  + dC2 * (u[i] * udx - XX[i])
                  + C2 * (du[i] * udx + u[i] * dudx - ex[i]);
        float dt  = dth * vh[i] + th * dvhv[i] + dC2 * uxv[i]
                  + C2 * (duxv[i] + uxdv[i])
                  + dths * (u[i] * udv - vh[i])
                  + ths * (du[i] * udv + u[i] * dudv - dvhv[i]);
        Jout[i * 3 + dd] = dRx + dt;
      }
    }
  }
}

extern "C" void kernel_launch(void* const* d_in, const int* in_sizes, int n_in,
                              void* d_out, int out_size, void* d_ws, size_t ws_size,
                              hipStream_t stream) {
  const float* x    = (const float*)d_in[0];
  const float* W_in = (const float*)d_in[1];
  const float* b_in = (const float*)d_in[2];
  const float* Ws   = (const float*)d_in[3];
  const float* bs   = (const float*)d_in[4];
  const float* Ww   = (const float*)d_in[5];
  const float* bw   = (const float*)d_in[6];
  const float* Wv   = (const float*)d_in[7];
  const float* bv   = (const float*)d_in[8];
  const int*   itp  = (const int*)d_in[9];
  unsigned short* wsW = (unsigned short*)d_ws;   // (7*16384 + 4096) bf16

  convert_weights<<<dim3((HOFF + HSZ + 255) / 256), dim3(256), 0, stream>>>(
      W_in, b_in, Ws, bs, Ww, Wv, wsW);
  nerfies_mfma<<<dim3(NBLK), dim3(THREADS), 0, stream>>>(
      x, bw, bv, wsW, itp, (float*)d_out);
}